// Round 1
// baseline (105.932 us; speedup 1.0000x reference)
//
#include <hip/hip_runtime.h>

// Problem constants (match reference): B=8, D=H=W=128, C=2, fp32.
constexpr int Bc = 8, Dc = 128, Hc = 128, Wc = 128;
constexpr int TOTAL = Bc * Dc * Hc * Wc;   // 2^24 voxels

__global__ __launch_bounds__(256) void affine_trilinear_kernel(
    const float* __restrict__ images,      // (B,D,H,W,C) fp32
    const float* __restrict__ mats,        // (B,3,4) fp32
    float2* __restrict__ out)              // (B,D,H,W,C) viewed as float2
{
    int idx = blockIdx.x * blockDim.x + threadIdx.x;
    if (idx >= TOTAL) return;

    const int w = idx & (Wc - 1);
    const int h = (idx >> 7) & (Hc - 1);
    const int d = (idx >> 14) & (Dc - 1);
    const int b = idx >> 21;

    // Per-batch affine params (tiny, L1-broadcast).
    const float* m = mats + b * 12;
    const float th00 = m[0] * 0.2f + 1.0f;
    const float th01 = m[1] * 0.2f;
    const float th02 = m[2] * 0.2f;
    const float th10 = m[4] * 0.2f;
    const float th11 = m[5] * 0.2f + 1.0f;
    const float th12 = m[6] * 0.2f;
    const float th20 = m[8] * 0.2f;
    const float th21 = m[9] * 0.2f;
    const float th22 = m[10] * 0.2f + 1.0f;
    const float t   = m[3] * 0.2f;                       // ref uses only m[0,3]
    const float off = 128.0f * (t + 0.5f) - 0.5f;        // dims are all 128

    // grid value: index - dim/2 - 0.5 = index - 64.5
    const float gx = (float)d - 64.5f;
    const float gy = (float)h - 64.5f;
    const float gz = (float)w - 64.5f;

    // ref = grid @ theta^T + off
    const float r0 = gx * th00 + gy * th01 + gz * th02 + off;
    const float r1 = gx * th10 + gy * th11 + gz * th12 + off;
    const float r2 = gx * th20 + gy * th21 + gz * th22 + off;

    const int i0 = (int)floorf(r0);
    const int i1 = (int)floorf(r1);
    const int i2 = (int)floorf(r2);

    // Per-axis clamped corner locations + weights (vs the CLAMPED location,
    // exactly as the reference: max(1 - |ref - loc|, 0)).
    const int l0a = min(max(i0,     0), Dc - 1);
    const int l0b = min(max(i0 + 1, 0), Dc - 1);
    const int l1a = min(max(i1,     0), Hc - 1);
    const int l1b = min(max(i1 + 1, 0), Hc - 1);
    const int l2a = min(max(i2,     0), Wc - 1);
    const int l2b = min(max(i2 + 1, 0), Wc - 1);

    const float w0a = fmaxf(1.0f - fabsf(r0 - (float)l0a), 0.0f);
    const float w0b = fmaxf(1.0f - fabsf(r0 - (float)l0b), 0.0f);
    const float w1a = fmaxf(1.0f - fabsf(r1 - (float)l1a), 0.0f);
    const float w1b = fmaxf(1.0f - fabsf(r1 - (float)l1b), 0.0f);
    const float w2a = fmaxf(1.0f - fabsf(r2 - (float)l2a), 0.0f);
    const float w2b = fmaxf(1.0f - fabsf(r2 - (float)l2b), 0.0f);

    const float2* img = (const float2*)images + (size_t)b * (Dc * Hc * Wc);

    float acc0 = 0.0f, acc1 = 0.0f;
    #pragma unroll
    for (int s = 0; s < 8; ++s) {
        const int s0 = (s >> 2) & 1;
        const int s1 = (s >> 1) & 1;
        const int s2 = s & 1;
        const int   l0 = s0 ? l0b : l0a;
        const int   l1 = s1 ? l1b : l1a;
        const int   l2 = s2 ? l2b : l2a;
        const float wt = (s0 ? w0b : w0a) * (s1 ? w1b : w1a) * (s2 ? w2b : w2a);
        const float2 v = img[((size_t)l0 * Hc + l1) * Wc + l2];
        acc0 = fmaf(v.x, wt, acc0);
        acc1 = fmaf(v.y, wt, acc1);
    }

    out[idx] = make_float2(acc0, acc1);
}

extern "C" void kernel_launch(void* const* d_in, const int* in_sizes, int n_in,
                              void* d_out, int out_size, void* d_ws, size_t ws_size,
                              hipStream_t stream) {
    const float* images = (const float*)d_in[0];
    const float* mats   = (const float*)d_in[1];
    float2* out         = (float2*)d_out;

    const int threads = 256;
    const int blocks  = TOTAL / threads;   // 65536
    affine_trilinear_kernel<<<blocks, threads, 0, stream>>>(images, mats, out);
}

// Round 2
// 66.756 us; speedup vs baseline: 1.5868x; 1.5868x over previous
//
#include <hip/hip_runtime.h>

// Problem constants (match reference): B=8, D=H=W=128, C=2, fp32.
constexpr int Bc = 8, Dc = 128, Hc = 128, Wc = 128;

// 16B vector with (claimed) 16B alignment; actual runtime addresses are 8B
// aligned (float2 granularity). CDNA global loads only require dword
// alignment (unaligned-access mode), so global_load_dwordx4 at 8B-aligned
// addresses is fine.
typedef float float4v __attribute__((ext_vector_type(4)));

__global__ __launch_bounds__(256) void affine_trilinear_kernel(
    const float* __restrict__ images,      // (B,D,H,W,C) fp32
    const float* __restrict__ mats,        // (B,3,4) fp32
    float2* __restrict__ out)              // (B,D,H,W,C) viewed as float2
{
    const int tid    = threadIdx.x;
    const int lane_w = tid & 63;           // 64 consecutive w per wave
    const int lane_h = tid >> 6;           // 4 h rows per block (L1 row reuse)

    const int bi = blockIdx.x;
    const int wh = bi & 1;                 // which w half
    const int h4 = (bi >> 1) & 31;
    const int d  = (bi >> 6) & (Dc - 1);
    const int b  = bi >> 13;               // uniform per block -> scalar loads

    const int w = wh * 64 + lane_w;
    const int h = h4 * 4 + lane_h;

    const float* m = mats + b * 12;
    const float th00 = m[0] * 0.2f + 1.0f;
    const float th01 = m[1] * 0.2f;
    const float th02 = m[2] * 0.2f;
    const float th10 = m[4] * 0.2f;
    const float th11 = m[5] * 0.2f + 1.0f;
    const float th12 = m[6] * 0.2f;
    const float th20 = m[8] * 0.2f;
    const float th21 = m[9] * 0.2f;
    const float th22 = m[10] * 0.2f + 1.0f;
    const float t   = m[3] * 0.2f;                 // ref uses only m[0,3]
    const float off = 128.0f * (t + 0.5f) - 0.5f;  // dims are all 128

    // grid value: index - dim/2 - 0.5 = index - 64.5
    const float gx = (float)d - 64.5f;
    const float gy = (float)h - 64.5f;
    const float gz = (float)w - 64.5f;

    const float r0 = gx * th00 + gy * th01 + gz * th02 + off;
    const float r1 = gx * th10 + gy * th11 + gz * th12 + off;
    const float r2 = gx * th20 + gy * th21 + gz * th22 + off;

    const int i0 = (int)floorf(r0);
    const int i1 = (int)floorf(r1);
    const int i2 = (int)floorf(r2);

    // d and h axes: per-corner clamped loc + weight (vs CLAMPED loc, as ref).
    const int l0a = min(max(i0,     0), Dc - 1);
    const int l0b = min(max(i0 + 1, 0), Dc - 1);
    const int l1a = min(max(i1,     0), Hc - 1);
    const int l1b = min(max(i1 + 1, 0), Hc - 1);

    const float w0a = fmaxf(1.0f - fabsf(r0 - (float)l0a), 0.0f);
    const float w0b = fmaxf(1.0f - fabsf(r0 - (float)l0b), 0.0f);
    const float w1a = fmaxf(1.0f - fabsf(r1 - (float)l1a), 0.0f);
    const float w1b = fmaxf(1.0f - fabsf(r1 - (float)l1b), 0.0f);

    // w axis: both corners come from ONE 16B pair load at bp (covers float2
    // elements bp and bp+1). Remap the two corner weights onto (lo,hi):
    //   interior       : va=lo, vb=hi
    //   i2 < 0 (clamp) : va=lo, vb=lo  -> wlo = w2a+w2b, whi = 0
    //   i2 > 126       : va=hi, vb=hi  -> wlo = 0,       whi = w2a+w2b
    const int bp  = min(max(i2, 0), Wc - 2);       // pair base in [0,126]
    const int l2a = min(max(i2,     0), Wc - 1);
    const int l2b = min(max(i2 + 1, 0), Wc - 1);
    const float w2a = fmaxf(1.0f - fabsf(r2 - (float)l2a), 0.0f);
    const float w2b = fmaxf(1.0f - fabsf(r2 - (float)l2b), 0.0f);
    const float wlo = (i2 > 126) ? 0.0f        : (w2a + ((i2 < 0) ? w2b : 0.0f));
    const float whi = (i2 > 126) ? (w2a + w2b) : ((i2 < 0) ? 0.0f : w2b);

    const float2* img = (const float2*)images + (size_t)b * (Dc * Hc * Wc);

    float acc0 = 0.0f, acc1 = 0.0f;
    #pragma unroll
    for (int s = 0; s < 4; ++s) {
        const int   l0  = (s & 2) ? l0b : l0a;
        const int   l1  = (s & 1) ? l1b : l1a;
        const float wdh = ((s & 2) ? w0b : w0a) * ((s & 1) ? w1b : w1a);
        const float4v v = *(const float4v*)(img + ((size_t)l0 * Hc + l1) * Wc + bp);
        // channels: lo = (v.x, v.y), hi = (v.z, v.w)
        const float p0 = v.x * wlo + v.z * whi;
        const float p1 = v.y * wlo + v.w * whi;
        acc0 = fmaf(p0, wdh, acc0);
        acc1 = fmaf(p1, wdh, acc1);
    }

    out[(((size_t)b * Dc + d) * Hc + h) * Wc + w] = make_float2(acc0, acc1);
}

extern "C" void kernel_launch(void* const* d_in, const int* in_sizes, int n_in,
                              void* d_out, int out_size, void* d_ws, size_t ws_size,
                              hipStream_t stream) {
    const float* images = (const float*)d_in[0];
    const float* mats   = (const float*)d_in[1];
    float2* out         = (float2*)d_out;

    const int threads = 256;
    const int blocks  = Bc * Dc * 32 * 2;  // 65536: (b, d, h/4, w-half)
    affine_trilinear_kernel<<<blocks, threads, 0, stream>>>(images, mats, out);
}